// Round 8
// baseline (16720.174 us; speedup 1.0000x reference)
//
#include <hip/hip_runtime.h>
#include <stdint.h>

// Problem constants
#define BB   64
#define TT   512
#define DIN  512
#define HH   1024
#define DOUT 512

// ============================ ROUND 8 DESIGN =============================
// r1-r6 wall: all cross-WG sync used sc1 (device scope) which bypasses the
// XCD L2 -> ~2000cy congested LLC RTT per dependency (r6 measured: one
// extra serialized RTT = +2130 cy/step). Fix: run each group (16 L0 WGs +
// 16 L1 WGs) on ONE XCD and sync through its shared L2 with sc0.
//
// r7 lesson: designs whose failure mode is a HANG return zero information.
// Round 8 makes every assumption degradable:
//  1) Deterministic roles: 256 WGs; XCD = blockIdx%8 (standard round-robin
//     dispatch mapping, same one XCD-swizzle exploits); group g = XCD g;
//     blockIdx%8 >= 4 exits. All 128 roles ALWAYS filled -> no starvation.
//  2) Dual-scope publish: each 16B chunk stored TWICE — sc0 (XCD L2,
//     updates any sentinel line in place) and sc1 (LLC, the r1-r5 proven
//     path). Same value -> no ordering hazard.
//  3) Watchdog-sticky poll: spin sc0 (~300cy RTT); after 8192 failures
//     (~1.25ms >> any legit wait, << timeout) the wave PERMANENTLY falls
//     back to sc1 polling. Worst case = correct run at ~sc1 speed +1.3ms.
//
// SYNC remains data-is-the-flag (r6: flag indirection costs a full RTT):
// tanh output is finite |h|<=1 so f2bf never emits 0x7FFF -> 0x7FFF7FFF is
// unreachable; state arrays sentinel-poisoned each launch; write-once per
// location; dword stores atomic -> non-sentinel IS the data.
// POLLS ARE FUSED (issue + s_waitcnt in ONE asm block) — r2 lesson.
// =========================================================================
#define GROUPS        4
#define ROWS          16
#define WGS_PER_GROUP 16
#define NSLICE        64
#define THREADS       512
#define NW            8
#define NWG_LAUNCH    256           // 128 active roles + 128 exiters
#define WDOG          8192          // sc0 attempts before sticky sc1 fallback
#define PSTR          18            // LDS parts stride: uniform 2-way (free)
#define PBUF          (NW * 4 * 16 * PSTR)
#define SSTR          36            // stage stride (dwords)
#define SENT          0x7fff7fffu   // two NaN bf16 halves; unreachable output

typedef __attribute__((ext_vector_type(8))) short frag8;        // 8 x bf16
typedef __attribute__((ext_vector_type(4))) float f32x4;        // MFMA acc
typedef __attribute__((ext_vector_type(4))) unsigned int u32x4; // asm payload

union U4F8 { u32x4 u; frag8 f; };

__device__ __forceinline__ float bf2f(unsigned short u) {
  union { unsigned int i; float f; } v; v.i = ((unsigned int)u) << 16; return v.f;
}
__device__ __forceinline__ unsigned short f2bf(float f) {
  union { float f; unsigned int i; } v; v.f = f;
  unsigned int x = v.i;
  x += 0x7fffu + ((x >> 16) & 1u);   // RNE
  return (unsigned short)(x >> 16);
}
__device__ __forceinline__ frag8 ld8f32(const float* p) {
  frag8 r;
#pragma unroll
  for (int j = 0; j < 8; ++j) r[j] = (short)f2bf(p[j]);
  return r;
}

// ---- fused polling loads: 4 dwordx4 + ONE waitcnt in a single asm block
// ("=&v" early-clobber REQUIRED; never split issue/wait across C++ code).
// sc0 variant: L1-bypass -> XCD-shared L2.  sc1 variant: L2-bypass -> LLC.
#define DEF_LDX4_POLL(NAME, FLAGS)                                           \
__device__ __forceinline__ bool NAME(frag8 a[4], const unsigned short* p) {  \
  u32x4 t0, t1, t2, t3;                                                      \
  asm volatile(                                                              \
      "global_load_dwordx4 %0, %4, off " FLAGS "\n\t"                        \
      "global_load_dwordx4 %1, %4, off offset:64 " FLAGS "\n\t"              \
      "global_load_dwordx4 %2, %4, off offset:128 " FLAGS "\n\t"             \
      "global_load_dwordx4 %3, %4, off offset:192 " FLAGS "\n\t"             \
      "s_waitcnt vmcnt(0)"                                                   \
      : "=&v"(t0), "=&v"(t1), "=&v"(t2), "=&v"(t3)                           \
      : "v"(p)                                                               \
      : "memory");                                                           \
  bool ok = (t0[0] != SENT) & (t0[1] != SENT) & (t0[2] != SENT) & (t0[3] != SENT) \
          & (t1[0] != SENT) & (t1[1] != SENT) & (t1[2] != SENT) & (t1[3] != SENT) \
          & (t2[0] != SENT) & (t2[1] != SENT) & (t2[2] != SENT) & (t2[3] != SENT) \
          & (t3[0] != SENT) & (t3[1] != SENT) & (t3[2] != SENT) & (t3[3] != SENT); \
  U4F8 u;                                                                    \
  u.u = t0; a[0] = u.f;  u.u = t1; a[1] = u.f;                               \
  u.u = t2; a[2] = u.f;  u.u = t3; a[3] = u.f;                               \
  return __ballot(ok) == ~0ull;                                              \
}
DEF_LDX4_POLL(ldx4_poll_sc0, "sc0")
DEF_LDX4_POLL(ldx4_poll_sc1, "sc1")

// watchdog-sticky poll: sc0 fast path; after WDOG failures this wave
// permanently switches to the sc1 (device-scope, r1-r5 proven) path.
// Control flow is wave-uniform (poll result is a full-wave ballot).
__device__ __forceinline__ void poll256(frag8 a[4], const unsigned short* p,
                                        bool& sc1mode) {
  if (!sc1mode) {
    if (ldx4_poll_sc0(a, p)) return;
    for (int i = 0; i < WDOG; ++i) {
      __builtin_amdgcn_s_sleep(1);
      if (ldx4_poll_sc0(a, p)) return;
    }
    sc1mode = true;                  // sc0 visibility broken: stop paying for it
  }
  while (!ldx4_poll_sc1(a, p)) { __builtin_amdgcn_s_sleep(1); }
}
// dual-scope publish: same 16B, same value, both cache scopes.
__device__ __forceinline__ void st128_dual(unsigned int* p, u32x4 v) {
  asm volatile(
      "global_store_dwordx4 %0, %1, off sc0\n\t"
      "global_store_dwordx4 %0, %1, off sc1"
      :: "v"(p), "v"(v) : "memory");
}

// One RNN layer scan step-loop. L0: X = fp32 x (register-prefetched under
// the poll), state seq = h1seq. L1: X = bf16 h1seq (tail-polled), state
// seq = h2seq. S layout: [row][t][HH] bf16, write-once per location.
template<int KIN, bool L0>
__device__ void scan_body(const void* Xv,
                          const float* Wih, const float* Whh,
                          const float* bih, const float* bhh,
                          unsigned short* S,
                          int g, int s, float* parts, unsigned int* stage)
{
  constexpr int KIT_IN = KIN / (NW * 32);   // L0: 2, L1: 4
  constexpr int KIT_HH = HH  / (NW * 32);   // 4

  const int j0  = s * NSLICE;
  const int r0  = g * ROWS;
  const int tid = threadIdx.x;
  const int w   = tid >> 6;                 // wave 0..7 (K-split)
  const int l   = tid & 63;
  const int lm  = l & 15;
  const int lq  = l >> 4;

  bool sc1mode = false;                     // sticky per-wave fallback state

  // ---- preload weights to VGPR frags (fp32 -> bf16 once) ----
  // B-frag: lane holds W[n = j0+nt*16+lm][k = w*(K/8) + kit*32 + lq*8 .. +7]
  frag8 wih_f[KIT_IN][4];
  frag8 whh_f[KIT_HH][4];
#pragma unroll
  for (int kit = 0; kit < KIT_IN; ++kit)
#pragma unroll
    for (int nt = 0; nt < 4; ++nt) {
      int n = j0 + nt * 16 + lm;
      int k = w * (KIN / NW) + kit * 32 + lq * 8;
      wih_f[kit][nt] = ld8f32(Wih + (size_t)n * KIN + k);
    }
#pragma unroll
  for (int kit = 0; kit < KIT_HH; ++kit)
#pragma unroll
    for (int nt = 0; nt < 4; ++nt) {
      int n = j0 + nt * 16 + lm;
      int k = w * (HH / NW) + kit * 32 + lq * 8;
      whh_f[kit][nt] = ld8f32(Whh + (size_t)n * HH + k);
    }

  // pass2: thread -> (row = tid&15, 2 contiguous cols at (tid>>4)*2)
  const int erow = tid & 15;
  const int ecg  = tid >> 4;               // 0..31
  float bias2[2];
#pragma unroll
  for (int j = 0; j < 2; ++j) {
    int c = j0 + ecg * 2 + j;
    bias2[j] = bih[c] + bhh[c];
  }
  // publisher: thread < 128 -> (row = tid>>3, 8 cols at (tid&7)*8)
  const int prow = tid >> 3;
  const int pc8  = tid & 7;

  // per-lane A-frag source offset within a timestep row
  const size_t koff = (size_t)w * (KIN / NW) + (size_t)lq * 8;

  // ---- stage x(0) into registers ----
  float4 xa[2 * KIT_IN];                    // L0 fp32 prefetch
  frag8  xf[KIT_IN];                        // L1 polled bf16 frags
  if constexpr (L0) {
    const float* xr = (const float*)Xv + ((size_t)(r0 + lm) * TT + 0) * KIN + koff;
#pragma unroll
    for (int kit = 0; kit < KIT_IN; ++kit) {
      xa[2 * kit]     = *(const float4*)(xr + kit * 32);
      xa[2 * kit + 1] = *(const float4*)(xr + kit * 32 + 4);
    }
  } else {
    const unsigned short* px = (const unsigned short*)Xv
        + ((size_t)(r0 + lm) * TT + 0) * KIN + koff;
    poll256(xf, px, sc1mode);
  }

  for (int t = 0; t < TT; ++t) {
    f32x4 acc[4];
#pragma unroll
    for (int nt = 0; nt < 4; ++nt) acc[nt] = (f32x4){0.f, 0.f, 0.f, 0.f};

    // ---- 1) x-projection: register-only at step head ----
    if constexpr (L0) {
#pragma unroll
      for (int kit = 0; kit < KIT_IN; ++kit) {
        const float* f0 = (const float*)&xa[2 * kit];
        const float* f1 = (const float*)&xa[2 * kit + 1];
        frag8 a;
#pragma unroll
        for (int j = 0; j < 4; ++j) {
          a[j]     = (short)f2bf(f0[j]);
          a[4 + j] = (short)f2bf(f1[j]);
        }
#pragma unroll
        for (int nt = 0; nt < 4; ++nt)
          acc[nt] = __builtin_amdgcn_mfma_f32_16x16x32_bf16(a, wih_f[kit][nt], acc[nt], 0, 0, 0);
      }
      // ---- 2) issue x(t+1) prefetch BEFORE the poll: the poll's vmcnt(0)
      // drains it, so its HBM latency rides entirely under the spin.
      if (t + 1 < TT) {
        const float* xr = (const float*)Xv
            + ((size_t)(r0 + lm) * TT + (t + 1)) * KIN + koff;
#pragma unroll
        for (int kit = 0; kit < KIT_IN; ++kit) {
          xa[2 * kit]     = *(const float4*)(xr + kit * 32);
          xa[2 * kit + 1] = *(const float4*)(xr + kit * 32 + 4);
        }
      }
    } else {
#pragma unroll
      for (int kit = 0; kit < KIT_IN; ++kit)
#pragma unroll
        for (int nt = 0; nt < 4; ++nt)
          acc[nt] = __builtin_amdgcn_mfma_f32_16x16x32_bf16(xf[kit], wih_f[kit][nt], acc[nt], 0, 0, 0);
    }

    // ---- 3) own-state poll (XCD-local L2 spin, sc1 fallback) + h-MFMAs ----
    if (t > 0) {
      const unsigned short* ph = S + ((size_t)(r0 + lm) * TT + (t - 1)) * HH
                                   + (size_t)w * (HH / NW) + lq * 8;
      frag8 hf[KIT_HH];
      poll256(hf, ph, sc1mode);
#pragma unroll
      for (int kit = 0; kit < KIT_HH; ++kit)
#pragma unroll
        for (int nt = 0; nt < 4; ++nt)
          acc[nt] = __builtin_amdgcn_mfma_f32_16x16x32_bf16(hf[kit], whh_f[kit][nt], acc[nt], 0, 0, 0);
    }

    // ---- 4) pass1: K-split partials to LDS (double-buffered) ----
    // C/D layout: col = lane&15, row = (lane>>4)*4 + reg  [verified m89/m91]
    float* pb = parts + (t & 1) * PBUF;
#pragma unroll
    for (int nt = 0; nt < 4; ++nt)
#pragma unroll
      for (int r = 0; r < 4; ++r)
        pb[((w * 4 + nt) * 16 + lq * 4 + r) * PSTR + lm] = acc[nt][r];
    __syncthreads();

    // ---- 5) pass2: reduce 8 K-chunks, tanh, pack 2 cols -> LDS stage ----
    unsigned int hb2 = 0;
#pragma unroll
    for (int j = 0; j < 2; ++j) {
      int c  = ecg * 2 + j;
      int nt = c >> 4;
      int lc = c & 15;
      float sm = 0.f;
#pragma unroll
      for (int w8 = 0; w8 < NW; ++w8)
        sm += pb[((w8 * 4 + nt) * 16 + erow) * PSTR + lc];
      float u = sm + bias2[j];
      float e = __expf(2.0f * u);               // tanh via exp, inf-safe
      float hv = 1.0f - 2.0f / (e + 1.0f);      // finite, |hv|<=1, NEVER NaN
      hb2 |= (unsigned int)f2bf(hv) << (16 * j);
    }
    stage[erow * SSTR + ecg] = hb2;
    __syncthreads();

    // ---- 6) publish: 128 threads x one 16B chunk, stored to BOTH scopes
    // (sc0: XCD L2 in-place update; sc1: LLC for fallback consumers).
    if (tid < 128) {
      u32x4 v = *(const u32x4*)(stage + prow * SSTR + pc8 * 4);
      unsigned short* dst = S + ((size_t)(r0 + prow) * TT + t) * HH + j0 + pc8 * 8;
      st128_dual((unsigned int*)dst, v);
    }
    // No third barrier: stage(t) readers (tid<128) pass barrier #1 of step
    // t+1 only after reading; parts reuse at t+2 is ordered by t+1's two
    // barriers. Threads >=128 run ahead — their polls are the sync.

    // ---- 7) L1: tail-poll x(t+1) = h1[t+1] (L0 runs ahead; usually ready)
    if constexpr (!L0) {
      if (t + 1 < TT) {
        const unsigned short* px = (const unsigned short*)Xv
            + ((size_t)(r0 + lm) * TT + (t + 1)) * KIN + koff;
        poll256(xf, px, sc1mode);
      }
    }
  }
}

__global__ __launch_bounds__(THREADS, 1)
void rnn_fused(const float* x,
               const float* Wih0, const float* Whh0, const float* bih0, const float* bhh0,
               const float* Wih1, const float* Whh1, const float* bih1, const float* bhh1,
               unsigned short* h1seq, unsigned short* h2seq)
{
  __shared__ float parts[2 * PBUF];
  __shared__ unsigned int stage[16 * SSTR];

  // Deterministic placement-affine roles (no getreg, no atomics, no hangs):
  // round-robin dispatch maps blockIdx%8 -> XCD, so group g = classes
  // {blockIdx%8 == g} is XCD-pure. If the mapping ever differs, sync
  // degrades to the sc1 fallback path — correct, just slower.
  const int wg  = blockIdx.x;
  const int xcd = wg & 7;
  const int k   = wg >> 3;                 // 0..31
  if (xcd >= GROUPS || k >= 2 * WGS_PER_GROUP) return;   // exiters
  const int g = xcd;
  if (k < WGS_PER_GROUP) {
    scan_body<DIN, true>(x, Wih0, Whh0, bih0, bhh0, h1seq, g, k, parts, stage);
  } else {
    scan_body<HH, false>(h1seq, Wih1, Whh1, bih1, bhh1, h2seq, g,
                         k - WGS_PER_GROUP, parts, stage);
  }
}

// poison h1seq+h2seq with the sentinel every launch (ws is re-poisoned 0xAA
// between timed launches; 0xAA bf16 looks valid to the sentinel check, so
// this MUST run first).
__global__ void poison_kernel(uint4* __restrict__ p, int n4) {
  int i  = blockIdx.x * blockDim.x + threadIdx.x;
  int st = gridDim.x * blockDim.x;
  const uint4 v = make_uint4(SENT, SENT, SENT, SENT);
  for (; i < n4; i += st) p[i] = v;
}

// out[m][n] = h2seq[m][T-1] . Wfc[n] + bfc[n]
__global__ void fc_kernel(const unsigned short* __restrict__ h2seq,  // bf16
                          const float* __restrict__ Wfc,             // fp32
                          const float* __restrict__ bfc,             // fp32
                          float* __restrict__ out)                   // fp32
{
  int idx = blockIdx.x * blockDim.x + threadIdx.x;  // 32768 = 64*512
  int m = idx >> 9;
  int n = idx & 511;
  const unsigned short* hp = h2seq + ((size_t)m * TT + (TT - 1)) * HH;
  const float*          wp = Wfc + (size_t)n * HH;
  float acc = 0.f;
#pragma unroll 4
  for (int k = 0; k < HH; k += 4) {
    ushort4 hv = *(const ushort4*)(hp + k);
    float4  wv = *(const float4*)(wp + k);
    acc += bf2f(hv.x) * wv.x + bf2f(hv.y) * wv.y
         + bf2f(hv.z) * wv.z + bf2f(hv.w) * wv.w;
  }
  out[idx] = acc + bfc[n];
}

extern "C" void kernel_launch(void* const* d_in, const int* in_sizes, int n_in,
                              void* d_out, int out_size, void* d_ws, size_t ws_size,
                              hipStream_t stream)
{
  const float* x    = (const float*)d_in[0];
  const float* Wih0 = (const float*)d_in[1];
  const float* Whh0 = (const float*)d_in[2];
  const float* bih0 = (const float*)d_in[3];
  const float* bhh0 = (const float*)d_in[4];
  const float* Wih1 = (const float*)d_in[5];
  const float* Whh1 = (const float*)d_in[6];
  const float* bih1 = (const float*)d_in[7];
  const float* bhh1 = (const float*)d_in[8];
  const float* Wfc  = (const float*)d_in[9];
  const float* bfc  = (const float*)d_in[10];

  // ws: h1seq (64MB) | h2seq (64MB) — both write-once bf16 [B][T][H]
  unsigned char* ws = (unsigned char*)d_ws;
  unsigned short* h1seq = (unsigned short*)ws;
  unsigned short* h2seq = (unsigned short*)(ws + (size_t)BB * TT * HH * 2);

  // sentinel-poison both state arrays (128 MiB, ~25 us)
  poison_kernel<<<4096, 256, 0, stream>>>(
      (uint4*)ws, (int)(((size_t)BB * TT * HH * 2 * 2) / 16));

  // fused 2-layer pipelined scan; roles derived from blockIdx (XCD-affine)
  rnn_fused<<<NWG_LAUNCH, THREADS, 0, stream>>>(
      x, Wih0, Whh0, bih0, bhh0, Wih1, Whh1, bih1, bhh1, h1seq, h2seq);

  fc_kernel<<<(BB * DOUT) / 256, 256, 0, stream>>>(h2seq, Wfc, bfc, (float*)d_out);
}

// Round 9
// 3231.910 us; speedup vs baseline: 5.1735x; 5.1735x over previous
//
#include <hip/hip_runtime.h>
#include <stdint.h>

// Problem constants
#define BB   64
#define TT   512
#define DIN  512
#define HH   1024
#define DOUT 512

// 4 independent batch groups x 16 rows; per group 16 WGs each owning 64 cols;
// 8 waves/WG K-split (128 K each). Layer 1 runs concurrently (WGs 64..127).
//
// SYNC: data-is-the-flag over sc1 (device scope — r7/r8 refuted any cheaper
// scope: sc0 is SE-scope on gfx940+, not XCD-scope). Producers store h bf16
// (sc1); consumers spin on the DATA with NaN sentinel 0x7FFF7FFF (tanh
// output is finite |h|<=1, f2bf never emits 0x7FFF). State arrays sentinel-
// poisoned each launch; write-once per location; dword stores atomic ->
// non-sentinel IS the data.
//
// Round-9: PIPELINED SPIN. Fused polls sample the LLC once per RTT; the
// step's detect cost is max over 8 waves' sampling phases ~ RTT + P*(8/9).
// Halve P with a depth-2 staggered poll — implemented ENTIRELY inside one
// asm block (r2 lesson: in-flight asm loads must never cross compiler-
// visible code). Two slots ping-pong: each = 4 probe dwords + 4 payload
// dwordx4 to the SAME lines; when slot X's probes pass, the OTHER slot's
// payload was issued later -> sampled post-commit -> valid. Fail-safe: a
// full C++ sentinel re-check follows; any torn/ordering edge falls back to
// the r5 simple poll (stale reads are ALWAYS sentinel under write-once).
#define GROUPS        4
#define ROWS          16
#define WGS_PER_GROUP 16
#define NSLICE        64
#define THREADS       512
#define NW            8
#define PSTR          18            // LDS parts stride: uniform 2-way (free)
#define PBUF          (NW * 4 * 16 * PSTR)
#define SSTR          36            // stage stride (dwords)
#define SENT          0x7fff7fffu   // two NaN bf16 halves; unreachable output

typedef __attribute__((ext_vector_type(8))) short frag8;        // 8 x bf16
typedef __attribute__((ext_vector_type(4))) float f32x4;        // MFMA acc
typedef __attribute__((ext_vector_type(4))) unsigned int u32x4; // asm payload

union U4F8 { u32x4 u; frag8 f; };

__device__ __forceinline__ float bf2f(unsigned short u) {
  union { unsigned int i; float f; } v; v.i = ((unsigned int)u) << 16; return v.f;
}
__device__ __forceinline__ unsigned short f2bf(float f) {
  union { float f; unsigned int i; } v; v.f = f;
  unsigned int x = v.i;
  x += 0x7fffu + ((x >> 16) & 1u);   // RNE
  return (unsigned short)(x >> 16);
}
__device__ __forceinline__ frag8 ld8f32(const float* p) {
  frag8 r;
#pragma unroll
  for (int j = 0; j < 8; ++j) r[j] = (short)f2bf(p[j]);
  return r;
}

// ---- simple fused poll (r5-proven): 4 dwordx4 + ONE waitcnt in one asm
// block. Used for x tail-polls (usually ready) and as the fail-safe path.
__device__ __forceinline__ bool ldx4_poll(frag8 a[4], const unsigned short* p) {
  u32x4 t0, t1, t2, t3;
  asm volatile(
      "global_load_dwordx4 %0, %4, off sc1\n\t"
      "global_load_dwordx4 %1, %4, off offset:64 sc1\n\t"
      "global_load_dwordx4 %2, %4, off offset:128 sc1\n\t"
      "global_load_dwordx4 %3, %4, off offset:192 sc1\n\t"
      "s_waitcnt vmcnt(0)"
      : "=&v"(t0), "=&v"(t1), "=&v"(t2), "=&v"(t3)
      : "v"(p)
      : "memory");
  bool ok = (t0[0] != SENT) & (t0[1] != SENT) & (t0[2] != SENT) & (t0[3] != SENT)
          & (t1[0] != SENT) & (t1[1] != SENT) & (t1[2] != SENT) & (t1[3] != SENT)
          & (t2[0] != SENT) & (t2[1] != SENT) & (t2[2] != SENT) & (t2[3] != SENT)
          & (t3[0] != SENT) & (t3[1] != SENT) & (t3[2] != SENT) & (t3[3] != SENT);
  U4F8 u;
  u.u = t0; a[0] = u.f;  u.u = t1; a[1] = u.f;
  u.u = t2; a[2] = u.f;  u.u = t3; a[3] = u.f;
  return __ballot(ok) == ~0ull;
}
__device__ __forceinline__ void poll256(frag8 a[4], const unsigned short* p) {
  if (ldx4_poll(a, p)) return;
  for (;;) {
    __builtin_amdgcn_s_sleep(1);
    if (ldx4_poll(a, p)) return;
  }
}

// ---- depth-2 pipelined spin, all inside ONE asm block ----
// Slots X (scratch s*) and Y (out o*); per slot 4 probe dwords (%8-%15,
// first dword of each 16B granule) + 4 payload dwordx4. Queue invariant at
// PLP: vmcnt(12) lands at least the current-X probes (any older prefetch
// loads/stores from the caller drain first — harmless). Accept: X-probes
// pass -> Y payload (issued after X-probes, same lines) sampled later ->
// valid; symmetric for Y. s_sleep 12 (~768cy) staggers the two streams.
// Exits drain vmcnt(0) so no load is in flight past the asm. fl=1 -> o*.
__device__ __forceinline__ void poll256_fast(frag8 a[4], const unsigned short* p) {
  u32x4 o0, o1, o2, o3, s0, s1, s2, s3;
  unsigned int qa0, qa1, qa2, qa3, qb0, qb1, qb2, qb3;
  unsigned long long fl;
  asm volatile(
      "global_load_dword %8,  %17, off sc1\n\t"
      "global_load_dword %9,  %17, off offset:64 sc1\n\t"
      "global_load_dword %10, %17, off offset:128 sc1\n\t"
      "global_load_dword %11, %17, off offset:192 sc1\n\t"
      "global_load_dwordx4 %4, %17, off sc1\n\t"
      "global_load_dwordx4 %5, %17, off offset:64 sc1\n\t"
      "global_load_dwordx4 %6, %17, off offset:128 sc1\n\t"
      "global_load_dwordx4 %7, %17, off offset:192 sc1\n\t"
      "global_load_dword %12, %17, off sc1\n\t"
      "global_load_dword %13, %17, off offset:64 sc1\n\t"
      "global_load_dword %14, %17, off offset:128 sc1\n\t"
      "global_load_dword %15, %17, off offset:192 sc1\n\t"
      "global_load_dwordx4 %0, %17, off sc1\n\t"
      "global_load_dwordx4 %1, %17, off offset:64 sc1\n\t"
      "global_load_dwordx4 %2, %17, off offset:128 sc1\n\t"
      "global_load_dwordx4 %3, %17, off offset:192 sc1\n\t"
      "PLP%=:\n\t"
      "s_waitcnt vmcnt(12)\n\t"
      "s_mov_b64 %16, -1\n\t"
      "v_cmp_ne_u32 vcc, 0x7fff7fff, %8\n\t"
      "s_and_b64 %16, %16, vcc\n\t"
      "v_cmp_ne_u32 vcc, 0x7fff7fff, %9\n\t"
      "s_and_b64 %16, %16, vcc\n\t"
      "v_cmp_ne_u32 vcc, 0x7fff7fff, %10\n\t"
      "s_and_b64 %16, %16, vcc\n\t"
      "v_cmp_ne_u32 vcc, 0x7fff7fff, %11\n\t"
      "s_and_b64 %16, %16, vcc\n\t"
      "s_cmp_eq_u64 %16, -1\n\t"
      "s_cbranch_scc1 PE1%=\n\t"
      "global_load_dword %8,  %17, off sc1\n\t"
      "global_load_dword %9,  %17, off offset:64 sc1\n\t"
      "global_load_dword %10, %17, off offset:128 sc1\n\t"
      "global_load_dword %11, %17, off offset:192 sc1\n\t"
      "global_load_dwordx4 %4, %17, off sc1\n\t"
      "global_load_dwordx4 %5, %17, off offset:64 sc1\n\t"
      "global_load_dwordx4 %6, %17, off offset:128 sc1\n\t"
      "global_load_dwordx4 %7, %17, off offset:192 sc1\n\t"
      "s_sleep 12\n\t"
      "s_waitcnt vmcnt(12)\n\t"
      "s_mov_b64 %16, -1\n\t"
      "v_cmp_ne_u32 vcc, 0x7fff7fff, %12\n\t"
      "s_and_b64 %16, %16, vcc\n\t"
      "v_cmp_ne_u32 vcc, 0x7fff7fff, %13\n\t"
      "s_and_b64 %16, %16, vcc\n\t"
      "v_cmp_ne_u32 vcc, 0x7fff7fff, %14\n\t"
      "s_and_b64 %16, %16, vcc\n\t"
      "v_cmp_ne_u32 vcc, 0x7fff7fff, %15\n\t"
      "s_and_b64 %16, %16, vcc\n\t"
      "s_cmp_eq_u64 %16, -1\n\t"
      "s_cbranch_scc1 PE0%=\n\t"
      "global_load_dword %12, %17, off sc1\n\t"
      "global_load_dword %13, %17, off offset:64 sc1\n\t"
      "global_load_dword %14, %17, off offset:128 sc1\n\t"
      "global_load_dword %15, %17, off offset:192 sc1\n\t"
      "global_load_dwordx4 %0, %17, off sc1\n\t"
      "global_load_dwordx4 %1, %17, off offset:64 sc1\n\t"
      "global_load_dwordx4 %2, %17, off offset:128 sc1\n\t"
      "global_load_dwordx4 %3, %17, off offset:192 sc1\n\t"
      "s_sleep 12\n\t"
      "s_branch PLP%=\n\t"
      "PE1%=:\n\t"                 // X probes passed -> Y payload (o*) valid
      "s_waitcnt vmcnt(0)\n\t"
      "s_mov_b64 %16, 1\n\t"
      "s_branch PD%=\n\t"
      "PE0%=:\n\t"                 // Y probes passed -> X payload (s*) valid
      "s_waitcnt vmcnt(0)\n\t"
      "s_mov_b64 %16, 0\n\t"
      "PD%=:"
      : "=&v"(o0), "=&v"(o1), "=&v"(o2), "=&v"(o3),
        "=&v"(s0), "=&v"(s1), "=&v"(s2), "=&v"(s3),
        "=&v"(qa0), "=&v"(qa1), "=&v"(qa2), "=&v"(qa3),
        "=&v"(qb0), "=&v"(qb1), "=&v"(qb2), "=&v"(qb3),
        "=&s"(fl)
      : "v"(p)
      : "memory", "vcc", "scc");
  // select accepted slot (fl is wave-uniform) and FULL sentinel re-check —
  // stale data is always sentinel (write-once), so any ordering/torn edge
  // is caught here and resolved by the proven simple poll.
  const u32x4 t0 = fl ? o0 : s0;
  const u32x4 t1 = fl ? o1 : s1;
  const u32x4 t2 = fl ? o2 : s2;
  const u32x4 t3 = fl ? o3 : s3;
  bool ok = (t0[0] != SENT) & (t0[1] != SENT) & (t0[2] != SENT) & (t0[3] != SENT)
          & (t1[0] != SENT) & (t1[1] != SENT) & (t1[2] != SENT) & (t1[3] != SENT)
          & (t2[0] != SENT) & (t2[1] != SENT) & (t2[2] != SENT) & (t2[3] != SENT)
          & (t3[0] != SENT) & (t3[1] != SENT) & (t3[2] != SENT) & (t3[3] != SENT);
  if (__ballot(ok) == ~0ull) {
    U4F8 u;
    u.u = t0; a[0] = u.f;  u.u = t1; a[1] = u.f;
    u.u = t2; a[2] = u.f;  u.u = t3; a[3] = u.f;
    return;
  }
  poll256(a, p);                   // fail-safe: guaranteed progress
}
__device__ __forceinline__ void st128_sc1(unsigned int* p, u32x4 v) {
  asm volatile("global_store_dwordx4 %0, %1, off sc1" :: "v"(p), "v"(v) : "memory");
}

// One RNN layer scan step-loop. L0: X = fp32 x (register-prefetched under
// the poll), state seq = h1seq. L1: X = bf16 h1seq (tail-polled), state
// seq = h2seq. S layout: [row][t][HH] bf16, write-once per location.
template<int KIN, bool L0>
__device__ void scan_body(const void* Xv,
                          const float* Wih, const float* Whh,
                          const float* bih, const float* bhh,
                          unsigned short* S,
                          int g, int s, float* parts, unsigned int* stage)
{
  constexpr int KIT_IN = KIN / (NW * 32);   // L0: 2, L1: 4
  constexpr int KIT_HH = HH  / (NW * 32);   // 4

  const int j0  = s * NSLICE;
  const int r0  = g * ROWS;
  const int tid = threadIdx.x;
  const int w   = tid >> 6;                 // wave 0..7 (K-split)
  const int l   = tid & 63;
  const int lm  = l & 15;
  const int lq  = l >> 4;

  // ---- preload weights to VGPR frags (fp32 -> bf16 once) ----
  // B-frag: lane holds W[n = j0+nt*16+lm][k = w*(K/8) + kit*32 + lq*8 .. +7]
  frag8 wih_f[KIT_IN][4];
  frag8 whh_f[KIT_HH][4];
#pragma unroll
  for (int kit = 0; kit < KIT_IN; ++kit)
#pragma unroll
    for (int nt = 0; nt < 4; ++nt) {
      int n = j0 + nt * 16 + lm;
      int k = w * (KIN / NW) + kit * 32 + lq * 8;
      wih_f[kit][nt] = ld8f32(Wih + (size_t)n * KIN + k);
    }
#pragma unroll
  for (int kit = 0; kit < KIT_HH; ++kit)
#pragma unroll
    for (int nt = 0; nt < 4; ++nt) {
      int n = j0 + nt * 16 + lm;
      int k = w * (HH / NW) + kit * 32 + lq * 8;
      whh_f[kit][nt] = ld8f32(Whh + (size_t)n * HH + k);
    }

  // pass2: thread -> (row = tid&15, 2 contiguous cols at (tid>>4)*2)
  const int erow = tid & 15;
  const int ecg  = tid >> 4;               // 0..31
  float bias2[2];
#pragma unroll
  for (int j = 0; j < 2; ++j) {
    int c = j0 + ecg * 2 + j;
    bias2[j] = bih[c] + bhh[c];
  }
  // publisher: thread < 128 -> (row = tid>>3, 8 cols at (tid&7)*8)
  const int prow = tid >> 3;
  const int pc8  = tid & 7;

  // per-lane A-frag source offset within a timestep row
  const size_t koff = (size_t)w * (KIN / NW) + (size_t)lq * 8;

  // ---- stage x(0) into registers ----
  float4 xa[2 * KIT_IN];                    // L0 fp32 prefetch
  frag8  xf[KIT_IN];                        // L1 polled bf16 frags
  if constexpr (L0) {
    const float* xr = (const float*)Xv + ((size_t)(r0 + lm) * TT + 0) * KIN + koff;
#pragma unroll
    for (int kit = 0; kit < KIT_IN; ++kit) {
      xa[2 * kit]     = *(const float4*)(xr + kit * 32);
      xa[2 * kit + 1] = *(const float4*)(xr + kit * 32 + 4);
    }
  } else {
    const unsigned short* px = (const unsigned short*)Xv
        + ((size_t)(r0 + lm) * TT + 0) * KIN + koff;
    poll256(xf, px);
  }

  for (int t = 0; t < TT; ++t) {
    f32x4 acc[4];
#pragma unroll
    for (int nt = 0; nt < 4; ++nt) acc[nt] = (f32x4){0.f, 0.f, 0.f, 0.f};

    // ---- 1) x-projection: register-only at step head ----
    if constexpr (L0) {
#pragma unroll
      for (int kit = 0; kit < KIT_IN; ++kit) {
        const float* f0 = (const float*)&xa[2 * kit];
        const float* f1 = (const float*)&xa[2 * kit + 1];
        frag8 a;
#pragma unroll
        for (int j = 0; j < 4; ++j) {
          a[j]     = (short)f2bf(f0[j]);
          a[4 + j] = (short)f2bf(f1[j]);
        }
#pragma unroll
        for (int nt = 0; nt < 4; ++nt)
          acc[nt] = __builtin_amdgcn_mfma_f32_16x16x32_bf16(a, wih_f[kit][nt], acc[nt], 0, 0, 0);
      }
      // ---- 2) issue x(t+1) prefetch BEFORE the poll: the poll's waitcnts
      // drain it, so its HBM latency rides entirely under the spin.
      if (t + 1 < TT) {
        const float* xr = (const float*)Xv
            + ((size_t)(r0 + lm) * TT + (t + 1)) * KIN + koff;
#pragma unroll
        for (int kit = 0; kit < KIT_IN; ++kit) {
          xa[2 * kit]     = *(const float4*)(xr + kit * 32);
          xa[2 * kit + 1] = *(const float4*)(xr + kit * 32 + 4);
        }
      }
    } else {
#pragma unroll
      for (int kit = 0; kit < KIT_IN; ++kit)
#pragma unroll
        for (int nt = 0; nt < 4; ++nt)
          acc[nt] = __builtin_amdgcn_mfma_f32_16x16x32_bf16(xf[kit], wih_f[kit][nt], acc[nt], 0, 0, 0);
    }

    // ---- 3) own-state PIPELINED poll + recurrence MFMAs ----
    if (t > 0) {
      const unsigned short* ph = S + ((size_t)(r0 + lm) * TT + (t - 1)) * HH
                                   + (size_t)w * (HH / NW) + lq * 8;
      frag8 hf[KIT_HH];
      poll256_fast(hf, ph);
#pragma unroll
      for (int kit = 0; kit < KIT_HH; ++kit)
#pragma unroll
        for (int nt = 0; nt < 4; ++nt)
          acc[nt] = __builtin_amdgcn_mfma_f32_16x16x32_bf16(hf[kit], whh_f[kit][nt], acc[nt], 0, 0, 0);
    }

    // ---- 4) pass1: K-split partials to LDS (double-buffered) ----
    // C/D layout: col = lane&15, row = (lane>>4)*4 + reg  [verified m89/m91]
    float* pb = parts + (t & 1) * PBUF;
#pragma unroll
    for (int nt = 0; nt < 4; ++nt)
#pragma unroll
      for (int r = 0; r < 4; ++r)
        pb[((w * 4 + nt) * 16 + lq * 4 + r) * PSTR + lm] = acc[nt][r];
    __syncthreads();

    // ---- 5) pass2: reduce 8 K-chunks, tanh, pack 2 cols -> LDS stage ----
    unsigned int hb2 = 0;
#pragma unroll
    for (int j = 0; j < 2; ++j) {
      int c  = ecg * 2 + j;
      int nt = c >> 4;
      int lc = c & 15;
      float sm = 0.f;
#pragma unroll
      for (int w8 = 0; w8 < NW; ++w8)
        sm += pb[((w8 * 4 + nt) * 16 + erow) * PSTR + lc];
      float u = sm + bias2[j];
      float e = __expf(2.0f * u);               // tanh via exp, inf-safe
      float hv = 1.0f - 2.0f / (e + 1.0f);      // finite, |hv|<=1, NEVER NaN
      hb2 |= (unsigned int)f2bf(hv) << (16 * j);
    }
    stage[erow * SSTR + ecg] = hb2;
    __syncthreads();

    // ---- 6) publish: 128 threads x one dwordx4 sc1 (16B, 8 cols each) ----
    if (tid < 128) {
      u32x4 v = *(const u32x4*)(stage + prow * SSTR + pc8 * 4);
      unsigned short* dst = S + ((size_t)(r0 + prow) * TT + t) * HH + j0 + pc8 * 8;
      st128_sc1((unsigned int*)dst, v);
    }
    // No third barrier: stage(t) readers (tid<128) pass barrier #1 of step
    // t+1 only after reading; parts reuse at t+2 is ordered by t+1's two
    // barriers. Threads >=128 run ahead — their polls are the sync.

    // ---- 7) L1: tail-poll x(t+1) = h1[t+1] (L0 runs ahead; usually ready)
    if constexpr (!L0) {
      if (t + 1 < TT) {
        const unsigned short* px = (const unsigned short*)Xv
            + ((size_t)(r0 + lm) * TT + (t + 1)) * KIN + koff;
        poll256(xf, px);
      }
    }
  }
}

__global__ __launch_bounds__(THREADS, 1)
void rnn_fused(const float* x,
               const float* Wih0, const float* Whh0, const float* bih0, const float* bhh0,
               const float* Wih1, const float* Whh1, const float* bih1, const float* bhh1,
               unsigned short* h1seq, unsigned short* h2seq)
{
  __shared__ float parts[2 * PBUF];
  __shared__ unsigned int stage[16 * SSTR];
  const int wg = blockIdx.x;
  if (wg < GROUPS * WGS_PER_GROUP) {
    const int g = wg / WGS_PER_GROUP, s = wg % WGS_PER_GROUP;
    scan_body<DIN, true>(x, Wih0, Whh0, bih0, bhh0, h1seq, g, s, parts, stage);
  } else {
    const int wg2 = wg - GROUPS * WGS_PER_GROUP;
    const int g = wg2 / WGS_PER_GROUP, s = wg2 % WGS_PER_GROUP;
    scan_body<HH, false>(h1seq, Wih1, Whh1, bih1, bhh1, h2seq, g, s, parts, stage);
  }
}

// poison h1seq+h2seq with the sentinel every launch (ws is re-poisoned 0xAA
// between timed launches; 0xAA bf16 looks valid to the sentinel check).
__global__ void poison_kernel(uint4* __restrict__ p, int n4) {
  int i  = blockIdx.x * blockDim.x + threadIdx.x;
  int st = gridDim.x * blockDim.x;
  const uint4 v = make_uint4(SENT, SENT, SENT, SENT);
  for (; i < n4; i += st) p[i] = v;
}

// out[m][n] = h2seq[m][T-1] . Wfc[n] + bfc[n]
__global__ void fc_kernel(const unsigned short* __restrict__ h2seq,  // bf16
                          const float* __restrict__ Wfc,             // fp32
                          const float* __restrict__ bfc,             // fp32
                          float* __restrict__ out)                   // fp32
{
  int idx = blockIdx.x * blockDim.x + threadIdx.x;  // 32768 = 64*512
  int m = idx >> 9;
  int n = idx & 511;
  const unsigned short* hp = h2seq + ((size_t)m * TT + (TT - 1)) * HH;
  const float*          wp = Wfc + (size_t)n * HH;
  float acc = 0.f;
#pragma unroll 4
  for (int k = 0; k < HH; k += 4) {
    ushort4 hv = *(const ushort4*)(hp + k);
    float4  wv = *(const float4*)(wp + k);
    acc += bf2f(hv.x) * wv.x + bf2f(hv.y) * wv.y
         + bf2f(hv.z) * wv.z + bf2f(hv.w) * wv.w;
  }
  out[idx] = acc + bfc[n];
}

extern "C" void kernel_launch(void* const* d_in, const int* in_sizes, int n_in,
                              void* d_out, int out_size, void* d_ws, size_t ws_size,
                              hipStream_t stream)
{
  const float* x    = (const float*)d_in[0];
  const float* Wih0 = (const float*)d_in[1];
  const float* Whh0 = (const float*)d_in[2];
  const float* bih0 = (const float*)d_in[3];
  const float* bhh0 = (const float*)d_in[4];
  const float* Wih1 = (const float*)d_in[5];
  const float* Whh1 = (const float*)d_in[6];
  const float* bih1 = (const float*)d_in[7];
  const float* bhh1 = (const float*)d_in[8];
  const float* Wfc  = (const float*)d_in[9];
  const float* bfc  = (const float*)d_in[10];

  // ws: h1seq (64MB) | h2seq (64MB) — both write-once bf16 [B][T][H]
  unsigned char* ws = (unsigned char*)d_ws;
  unsigned short* h1seq = (unsigned short*)ws;
  unsigned short* h2seq = (unsigned short*)(ws + (size_t)BB * TT * HH * 2);

  // sentinel-poison both state arrays (128 MiB, ~25 us)
  poison_kernel<<<4096, 256, 0, stream>>>(
      (uint4*)ws, (int)(((size_t)BB * TT * HH * 2 * 2) / 16));

  // fused 2-layer pipelined scan: WGs 0..63 = layer 0, 64..127 = layer 1
  rnn_fused<<<2 * GROUPS * WGS_PER_GROUP, THREADS, 0, stream>>>(
      x, Wih0, Whh0, bih0, bhh0, Wih1, Whh1, bih1, bhh1, h1seq, h2seq);

  fc_kernel<<<(BB * DOUT) / 256, 256, 0, stream>>>(h2seq, Wfc, bfc, (float*)d_out);
}